// Round 1
// baseline (442.208 us; speedup 1.0000x reference)
//
#include <hip/hip_runtime.h>
#include <hip/hip_bf16.h>

// GPT-2 attention block, MI355X. B=1 T=4096 C=1024 H=16 D=64.
// Pipeline: cvt(x)->bf16 ; W^T->bf16 ; QKV GEMM (MFMA bf16) -> Q,K,[V^T] ;
// flash attention (swapped-QK^T, online softmax) ; proj GEMM -> fp32 out.

typedef unsigned short u16;
typedef u16 u16x4 __attribute__((ext_vector_type(4)));
typedef u16 u16x8 __attribute__((ext_vector_type(8)));
typedef __bf16 bf16x8 __attribute__((ext_vector_type(8)));
typedef float f32x4 __attribute__((ext_vector_type(4)));

#define T_SEQ 4096
#define C_DIM 1024
#define NH 16
#define HD 64

static __device__ __forceinline__ u16 f2bf(float f) {
    __hip_bfloat16 h = __float2bfloat16(f);
    return __builtin_bit_cast(u16, h);
}

// Build an MFMA A/B fragment (16x16x32 bf16): elems[0:4] from `lo`, elems[4:8] from `hi`.
static __device__ __forceinline__ bf16x8 ldfrag(const u16* lo, const u16* hi) {
    u16x4 a = *(const u16x4*)lo;
    u16x4 b = *(const u16x4*)hi;
    u16x8 v = __builtin_shufflevector(a, b, 0, 1, 2, 3, 4, 5, 6, 7);
    return __builtin_bit_cast(bf16x8, v);
}

#define MFMA16(a, b, c) __builtin_amdgcn_mfma_f32_16x16x32_bf16((a), (b), (c), 0, 0, 0)

// ---------------- prep kernels ----------------

__global__ __launch_bounds__(256) void k_cvt_x(const float* __restrict__ x, u16* __restrict__ xb) {
    int i = (blockIdx.x * 256 + threadIdx.x) * 8;
    float4 a = *(const float4*)(x + i);
    float4 b = *(const float4*)(x + i + 4);
    u16x8 o;
    o[0] = f2bf(a.x); o[1] = f2bf(a.y); o[2] = f2bf(a.z); o[3] = f2bf(a.w);
    o[4] = f2bf(b.x); o[5] = f2bf(b.y); o[6] = f2bf(b.z); o[7] = f2bf(b.w);
    *(u16x8*)(xb + i) = o;
}

// src [R][Cc] f32 -> dst [Cc][R] bf16 (B^T layout for GEMM)
__global__ __launch_bounds__(256) void k_transpose_w(const float* __restrict__ src,
                                                     u16* __restrict__ dst, int R, int Cc) {
    __shared__ float tile[32][33];
    int bx = blockIdx.x * 32;  // col base in src
    int by = blockIdx.y * 32;  // row base in src
    int x = threadIdx.x, y = threadIdx.y;
#pragma unroll
    for (int i = 0; i < 32; i += 8)
        tile[y + i][x] = src[(by + y + i) * Cc + bx + x];
    __syncthreads();
#pragma unroll
    for (int i = 0; i < 32; i += 8)
        dst[(bx + y + i) * R + by + x] = f2bf(tile[x][y + i]);
}

// ---------------- GEMM: C[m][n] = sum_k A[m][k] * Bt[n][k] + bias[n] ----------------
// 128x128 tile, BK=32, 256 thr (2x2 waves, 64x64 each), MFMA 16x16x32 bf16.
// EPI=0: route to Q/K (bf16 [h][t][64]) and Vt (bf16 [h][64][t]).  EPI=1: fp32 out.

template <int EPI>
__global__ __launch_bounds__(256) void k_gemm(const u16* __restrict__ A, const u16* __restrict__ Bt,
                                              const float* __restrict__ bias,
                                              u16* __restrict__ outQ, u16* __restrict__ outK,
                                              u16* __restrict__ outVt, float* __restrict__ outF,
                                              int kdim) {
    __shared__ u16 Alds[128 * 32];
    __shared__ u16 Blds[128 * 32];
    const int tid = threadIdx.x;
    const int lane = tid & 63;
    const int wid = tid >> 6;
    const int wm = wid >> 1, wn = wid & 1;
    const int r16 = lane & 15, g = lane >> 4;
    const int m0 = blockIdx.x * 128, n0 = blockIdx.y * 128;

    f32x4 acc[4][4] = {};

    for (int k0 = 0; k0 < kdim; k0 += 32) {
        // reg-staged LDS fill: 512 u16x8 chunks per matrix half... (4096 elems = 512 chunks of 8)
#pragma unroll
        for (int i = 0; i < 2; ++i) {
            int chunk = i * 256 + tid;          // 0..511
            int row = chunk >> 2;               // 0..127
            int c = (chunk & 3) * 8;            // 0,8,16,24
            u16x8 va = *(const u16x8*)(A + (m0 + row) * kdim + k0 + c);
            u16x8 vb = *(const u16x8*)(Bt + (n0 + row) * kdim + k0 + c);
            *(u16x8*)(Alds + row * 32 + c) = va;
            *(u16x8*)(Blds + row * 32 + c) = vb;
        }
        __syncthreads();

        bf16x8 af[4], bfr[4];
#pragma unroll
        for (int mi = 0; mi < 4; ++mi) {
            const u16* p = Alds + (wm * 64 + mi * 16 + r16) * 32;
            af[mi] = ldfrag(p + g * 4, p + 16 + g * 4);
        }
#pragma unroll
        for (int ni = 0; ni < 4; ++ni) {
            const u16* p = Blds + (wn * 64 + ni * 16 + r16) * 32;
            bfr[ni] = ldfrag(p + g * 4, p + 16 + g * 4);
        }
#pragma unroll
        for (int mi = 0; mi < 4; ++mi)
#pragma unroll
            for (int ni = 0; ni < 4; ++ni)
                acc[mi][ni] = MFMA16(af[mi], bfr[ni], acc[mi][ni]);
        __syncthreads();
    }

    // C/D layout: col = lane&15, row = 4*(lane>>4) + r
    const int mbase = m0 + wm * 64;
    const int nbase = n0 + wn * 64;
    if (EPI == 0) {
#pragma unroll
        for (int ni = 0; ni < 4; ++ni) {
            const int n = nbase + ni * 16 + r16;
            const float bv = bias[n];
            const int part = n >> 10;  // 0=Q 1=K 2=V (uniform per block: n-tile of 128 never straddles)
            const int nr = n & 1023;
            const int h = nr >> 6, d = nr & 63;
#pragma unroll
            for (int mi = 0; mi < 4; ++mi) {
                const int mrow = mbase + mi * 16 + g * 4;
                if (part == 2) {
                    u16x4 pk;
#pragma unroll
                    for (int r = 0; r < 4; ++r) pk[r] = f2bf(acc[mi][ni][r] + bv);
                    *(u16x4*)(outVt + (h * HD + d) * T_SEQ + mrow) = pk;  // V^T: [h][d][t]
                } else {
                    u16* dst = (part == 1 ? outK : outQ) + (h * T_SEQ) * HD + d;
#pragma unroll
                    for (int r = 0; r < 4; ++r)
                        dst[(mrow + r) * HD] = f2bf(acc[mi][ni][r] + bv);
                }
            }
        }
    } else {
#pragma unroll
        for (int ni = 0; ni < 4; ++ni) {
            const int n = nbase + ni * 16 + r16;
            const float bv = bias[n];
#pragma unroll
            for (int mi = 0; mi < 4; ++mi) {
                const int mrow = mbase + mi * 16 + g * 4;
#pragma unroll
                for (int r = 0; r < 4; ++r)
                    outF[(mrow + r) * C_DIM + n] = acc[mi][ni][r] + bv;
            }
        }
    }
}

// ---------------- flash attention ----------------
// 512 thr = 8 waves; wave w owns q-rows [qb*128 + w*16, +16). KV tiles of 64 staged in LDS.
// Swapped QK^T: S^T = mfma(A=K, B=Q) -> lane holds S[kv = 16*tau + 4g + r][q = lane&15].
// P then feeds PV A-operand in-lane. O = mfma(P, V) with V^T rows from LDS.

__global__ __launch_bounds__(512) void k_flash(const u16* __restrict__ Qg, const u16* __restrict__ Kg,
                                               const u16* __restrict__ Vtg, u16* __restrict__ Oa) {
    __shared__ u16 Klds[64][80];  // pad 64->80 elems: breaks 128B-row-stride bank conflicts
    __shared__ u16 Vlds[64][80];

    const int tid = threadIdx.x;
    const int lane = tid & 63;
    const int wid = tid >> 6;
    const int r16 = lane & 15, g = lane >> 4;
    const int head = blockIdx.y;
    const int qb = 31 - blockIdx.x;  // reversed: longest blocks dispatch first
    const int q0 = qb * 128 + wid * 16;
    const int q_abs = q0 + r16;

    const u16* Qh = Qg + head * (T_SEQ * HD);
    const u16* Kh = Kg + head * (T_SEQ * HD);
    const u16* Vh = Vtg + head * (HD * T_SEQ);

    // Q fragments (B-operand): lane's own q-row, d split per MFMA k-layout
    const u16* qrow = Qh + q_abs * HD;
    const bf16x8 qf0 = ldfrag(qrow + g * 4, qrow + 16 + g * 4);        // d 0..31
    const bf16x8 qf1 = ldfrag(qrow + 32 + g * 4, qrow + 48 + g * 4);   // d 32..63

    f32x4 o[4] = {};
    float m = -1e30f, lsum = 0.f;
    const float CSC = 0.125f * 1.44269504088896f;  // scale * log2(e)

    const int kv_end = qb * 128 + 128;
    const int srow = tid >> 3;
    const int scol = (tid & 7) * 8;

    for (int kv0 = 0; kv0 < kv_end; kv0 += 64) {
        *(u16x8*)(&Klds[srow][scol]) = *(const u16x8*)(Kh + (kv0 + srow) * HD + scol);
        *(u16x8*)(&Vlds[srow][scol]) = *(const u16x8*)(Vh + srow * T_SEQ + kv0 + scol);
        __syncthreads();

        if (kv0 <= q0 + 15) {  // wave-uniform causal skip
            f32x4 s[4];
#pragma unroll
            for (int tau = 0; tau < 4; ++tau) {
                const u16* kr = &Klds[tau * 16 + r16][0];
                bf16x8 a0 = ldfrag(kr + g * 4, kr + 16 + g * 4);
                bf16x8 a1 = ldfrag(kr + 32 + g * 4, kr + 48 + g * 4);
                f32x4 z = {};
                z = MFMA16(a0, qf0, z);
                s[tau] = MFMA16(a1, qf1, z);
            }
            // mask + scale; lane's kv rows: kv0 + 16*tau + 4g + r ; q col = q_abs
            float sv[4][4];
            float mloc = -1e30f;
#pragma unroll
            for (int tau = 0; tau < 4; ++tau)
#pragma unroll
                for (int r = 0; r < 4; ++r) {
                    int kv_abs = kv0 + tau * 16 + g * 4 + r;
                    float v = (kv_abs <= q_abs) ? s[tau][r] * CSC : -1e30f;
                    sv[tau][r] = v;
                    mloc = fmaxf(mloc, v);
                }
            mloc = fmaxf(mloc, __shfl_xor(mloc, 16));
            mloc = fmaxf(mloc, __shfl_xor(mloc, 32));
            float mnew = fmaxf(m, mloc);
            float fac = exp2f(m - mnew);
            m = mnew;

            float ps = 0.f;
            u16 pb[4][4];
#pragma unroll
            for (int tau = 0; tau < 4; ++tau)
#pragma unroll
                for (int r = 0; r < 4; ++r) {
                    float p = exp2f(sv[tau][r] - mnew);
                    ps += p;
                    pb[tau][r] = f2bf(p);
                }
            ps += __shfl_xor(ps, 16);
            ps += __shfl_xor(ps, 32);
            lsum = lsum * fac + ps;

            // rescale O: o[n][r] belongs to q_local = 4g + r; stats live at lane (4g+r)
            float fr[4];
#pragma unroll
            for (int r = 0; r < 4; ++r) fr[r] = __shfl(fac, g * 4 + r);
#pragma unroll
            for (int n = 0; n < 4; ++n)
#pragma unroll
                for (int r = 0; r < 4; ++r) o[n][r] *= fr[r];

            // PV: A = P (m=q=lane&15, k=kv in-lane), B = V^T rows from LDS
#pragma unroll
            for (int ks = 0; ks < 2; ++ks) {
                u16x8 pa = {pb[2 * ks][0], pb[2 * ks][1], pb[2 * ks][2], pb[2 * ks][3],
                            pb[2 * ks + 1][0], pb[2 * ks + 1][1], pb[2 * ks + 1][2], pb[2 * ks + 1][3]};
                bf16x8 paf = __builtin_bit_cast(bf16x8, pa);
#pragma unroll
                for (int n = 0; n < 4; ++n) {
                    const u16* vr = &Vlds[n * 16 + r16][0];
                    bf16x8 vb = ldfrag(vr + ks * 32 + g * 4, vr + ks * 32 + 16 + g * 4);
                    o[n] = MFMA16(paf, vb, o[n]);
                }
            }
        }
        __syncthreads();
    }

    float linv[4];
#pragma unroll
    for (int r = 0; r < 4; ++r) linv[r] = 1.0f / __shfl(lsum, g * 4 + r);
#pragma unroll
    for (int n = 0; n < 4; ++n)
#pragma unroll
        for (int r = 0; r < 4; ++r) {
            int t = q0 + g * 4 + r;
            Oa[t * C_DIM + head * HD + n * 16 + r16] = f2bf(o[n][r] * linv[r]);
        }
}

// ---------------- launch ----------------

extern "C" void kernel_launch(void* const* d_in, const int* in_sizes, int n_in,
                              void* d_out, int out_size, void* d_ws, size_t ws_size,
                              hipStream_t stream) {
    const float* x      = (const float*)d_in[0];
    const float* W_attn = (const float*)d_in[1];
    const float* b_attn = (const float*)d_in[2];
    const float* W_proj = (const float*)d_in[3];
    const float* b_proj = (const float*)d_in[4];
    float* out = (float*)d_out;

    char* ws = (char*)d_ws;  // 48 MB used
    u16* xb  = (u16*)(ws);                       // 8 MB  x as bf16 [4096][1024]
    u16* Wat = (u16*)(ws + (8u << 20));          // 6 MB  W_attn^T bf16 [3072][1024]
    u16* Wpt = (u16*)(ws + (14u << 20));         // 2 MB  W_proj^T bf16 [1024][1024]
    u16* Qb  = (u16*)(ws + (16u << 20));         // 8 MB  [16][4096][64]
    u16* Kb  = (u16*)(ws + (24u << 20));         // 8 MB  [16][4096][64]
    u16* Vtb = (u16*)(ws + (32u << 20));         // 8 MB  [16][64][4096]
    u16* Ab  = (u16*)(ws + (40u << 20));         // 8 MB  attn out bf16 [4096][1024]

    k_cvt_x<<<2048, 256, 0, stream>>>(x, xb);
    k_transpose_w<<<dim3(96, 32), dim3(32, 8), 0, stream>>>(W_attn, Wat, 1024, 3072);
    k_transpose_w<<<dim3(32, 32), dim3(32, 8), 0, stream>>>(W_proj, Wpt, 1024, 1024);
    k_gemm<0><<<dim3(32, 24), 256, 0, stream>>>(xb, Wat, b_attn, Qb, Kb, Vtb, nullptr, 1024);
    k_flash<<<dim3(32, 16), 512, 0, stream>>>(Qb, Kb, Vtb, Ab);
    k_gemm<1><<<dim3(32, 8), 256, 0, stream>>>(Ab, Wpt, b_proj, nullptr, nullptr, nullptr, out, 1024);
}

// Round 2
// 235.377 us; speedup vs baseline: 1.8787x; 1.8787x over previous
//
#include <hip/hip_runtime.h>
#include <hip/hip_bf16.h>

// GPT-2 attention block, MI355X. B=1 T=4096 C=1024 H=16 D=64.
// R2: flash = 4 waves x 32q, double-buffered gload_lds staging, XOR-swizzled LDS,
//     contiguous-k fragment permutation (all LDS reads = ds_read_b128), O^T PV.
//     GEMM = m97 structure (BK=64, global_load_lds 16B, swizzle, b128 frags).

typedef unsigned short u16;
typedef u16 u16x4 __attribute__((ext_vector_type(4)));
typedef u16 u16x8 __attribute__((ext_vector_type(8)));
typedef __bf16 bf16x8 __attribute__((ext_vector_type(8)));
typedef float f32x4 __attribute__((ext_vector_type(4)));

#define T_SEQ 4096
#define C_DIM 1024
#define NH 16
#define HD 64
#define QSC 0.18033688f  // 0.125 * log2(e): folded into Q at QKV epilogue

static __device__ __forceinline__ u16 f2bf(float f) {
    __hip_bfloat16 h = __float2bfloat16(f);
    return __builtin_bit_cast(u16, h);
}

// 16B LDS read at byte offset (must be 16B aligned)
static __device__ __forceinline__ bf16x8 ldfr(const u16* base, int byteoff) {
    return __builtin_bit_cast(bf16x8, *(const u16x8*)(base + (byteoff >> 1)));
}

// async global->LDS, 16B per lane; LDS dest = wave-uniform base + lane*16
static __device__ __forceinline__ void gld_lds16(const void* g, void* l) {
    __builtin_amdgcn_global_load_lds((const __attribute__((address_space(1))) void*)g,
                                     (__attribute__((address_space(3))) void*)l, 16, 0, 0);
}

#define MFMA16(a, b, c) __builtin_amdgcn_mfma_f32_16x16x32_bf16((a), (b), (c), 0, 0, 0)

// ---------------- prep kernels ----------------

__global__ __launch_bounds__(256) void k_cvt_x(const float* __restrict__ x, u16* __restrict__ xb) {
    int i = (blockIdx.x * 256 + threadIdx.x) * 8;
    float4 a = *(const float4*)(x + i);
    float4 b = *(const float4*)(x + i + 4);
    u16x8 o;
    o[0] = f2bf(a.x); o[1] = f2bf(a.y); o[2] = f2bf(a.z); o[3] = f2bf(a.w);
    o[4] = f2bf(b.x); o[5] = f2bf(b.y); o[6] = f2bf(b.z); o[7] = f2bf(b.w);
    *(u16x8*)(xb + i) = o;
}

// src [R][Cc] f32 -> dst [Cc][R] bf16
__global__ __launch_bounds__(256) void k_transpose_w(const float* __restrict__ src,
                                                     u16* __restrict__ dst, int R, int Cc) {
    __shared__ float tile[32][33];
    int bx = blockIdx.x * 32;
    int by = blockIdx.y * 32;
    int x = threadIdx.x, y = threadIdx.y;
#pragma unroll
    for (int i = 0; i < 32; i += 8)
        tile[y + i][x] = src[(by + y + i) * Cc + bx + x];
    __syncthreads();
#pragma unroll
    for (int i = 0; i < 32; i += 8)
        dst[(bx + y + i) * R + by + x] = f2bf(tile[x][y + i]);
}

// ---------------- GEMM: C[m][n] = sum_k A[m][k]*Bt[n][k] + bias[n] ----------------
// 128x128 tile, BK=64, 4 waves (2x2), gload_lds staging with pre-swizzled source,
// contiguous-k frags (lane reads k=8g..8g+7 as one b128; both operands use same perm).

template <int EPI>
__global__ __launch_bounds__(256) void k_gemm(const u16* __restrict__ A, const u16* __restrict__ Bt,
                                              const float* __restrict__ bias,
                                              u16* __restrict__ outQ, u16* __restrict__ outK,
                                              u16* __restrict__ outVt, float* __restrict__ outF,
                                              int kd, int nbx) {
    __shared__ u16 Al[128 * 64];
    __shared__ u16 Bl[128 * 64];
    const int tid = threadIdx.x;
    const int lane = tid & 63;
    const int wid = tid >> 6;
    const int wm = wid >> 1, wn = wid & 1;
    const int c = lane & 15, g = lane >> 4;
    const int nwg = gridDim.x;
    const int swzb = ((int)blockIdx.x & 7) * (nwg >> 3) + ((int)blockIdx.x >> 3);
    const int m0 = (swzb % nbx) * 128;
    const int n0 = (swzb / nbx) * 128;
    const int srow = lane >> 3;
    const int sxu = (((lane & 7) * 16) ^ (srow << 4)) >> 1;  // pre-swizzled src col (u16)
    const int swa = (c & 7) << 4;                            // read-side swizzle key

    f32x4 acc[4][4] = {};

    for (int k0 = 0; k0 < kd; k0 += 64) {
#pragma unroll
        for (int i = 0; i < 4; ++i) {
            const int ch = wid * 4 + i;
            const int row = ch * 8 + srow;
            gld_lds16(A + (m0 + row) * kd + k0 + sxu, &Al[ch * 512]);
            gld_lds16(Bt + (n0 + row) * kd + k0 + sxu, &Bl[ch * 512]);
        }
        __syncthreads();
        bf16x8 af[4][2], bfm[4][2];
#pragma unroll
        for (int mi = 0; mi < 4; ++mi) {
            const u16* p = Al + (wm * 64 + mi * 16 + c) * 64;
            af[mi][0] = ldfr(p, (16 * g) ^ swa);
            af[mi][1] = ldfr(p, (64 + 16 * g) ^ swa);
        }
#pragma unroll
        for (int ni = 0; ni < 4; ++ni) {
            const u16* p = Bl + (wn * 64 + ni * 16 + c) * 64;
            bfm[ni][0] = ldfr(p, (16 * g) ^ swa);
            bfm[ni][1] = ldfr(p, (64 + 16 * g) ^ swa);
        }
#pragma unroll
        for (int mi = 0; mi < 4; ++mi)
#pragma unroll
            for (int ni = 0; ni < 4; ++ni) {
                acc[mi][ni] = MFMA16(af[mi][0], bfm[ni][0], acc[mi][ni]);
                acc[mi][ni] = MFMA16(af[mi][1], bfm[ni][1], acc[mi][ni]);
            }
        __syncthreads();
    }

    // C/D: lane(16g+c) reg r -> row = 4g+r, col = c
    const int mbase = m0 + wm * 64;
    const int nbase = n0 + wn * 64;
    if (EPI == 0) {
#pragma unroll
        for (int ni = 0; ni < 4; ++ni) {
            const int n = nbase + ni * 16 + c;
            const float bv = bias[n];
            const int part = n >> 10;  // 0=Q 1=K 2=V (uniform per block)
            const int nr = n & 1023;
            const int h = nr >> 6, d = nr & 63;
#pragma unroll
            for (int mi = 0; mi < 4; ++mi) {
                const int mrow = mbase + mi * 16 + g * 4;
                if (part == 2) {
                    u16x4 pk;
#pragma unroll
                    for (int r = 0; r < 4; ++r) pk[r] = f2bf(acc[mi][ni][r] + bv);
                    *(u16x4*)(outVt + (h * HD + d) * T_SEQ + mrow) = pk;  // V^T: [h][d][t]
                } else if (part == 1) {
                    u16* dst = outK + h * T_SEQ * HD + d;
#pragma unroll
                    for (int r = 0; r < 4; ++r) dst[(mrow + r) * HD] = f2bf(acc[mi][ni][r] + bv);
                } else {
                    u16* dst = outQ + h * T_SEQ * HD + d;
#pragma unroll
                    for (int r = 0; r < 4; ++r) dst[(mrow + r) * HD] = f2bf((acc[mi][ni][r] + bv) * QSC);
                }
            }
        }
    } else {
#pragma unroll
        for (int ni = 0; ni < 4; ++ni) {
            const int n = nbase + ni * 16 + c;
            const float bv = bias[n];
#pragma unroll
            for (int mi = 0; mi < 4; ++mi) {
                const int mrow = mbase + mi * 16 + g * 4;
#pragma unroll
                for (int r = 0; r < 4; ++r)
                    outF[(mrow + r) * C_DIM + n] = acc[mi][ni][r] + bv;
            }
        }
    }
}

// ---------------- flash attention ----------------
// 256 thr = 4 waves; wave owns 32 q-rows (2 halves of 16). KV tile 64, double-buffered.
// QK^T: S^T = mfma(A=K(perm'd rows), B=Q) with contiguous-k perm; K row for A-tile tau,
// frag-row p: kv = 32*(tau>>1) + 4*(tau&1) + 8*(p>>2) + (p&3). Lane(16g+c) then holds
// P[q=c][kv = 32ks+8g..+7] across regs -> feeds PV B-operand directly.
// PV: O^T = mfma(A=V^T, B=P); all softmax state lane-local per q=c.

static __device__ __forceinline__ void soft_half(f32x4 s[4], int qabs, int kv0, int g,
                                                 bool domask, float& m, float& l,
                                                 f32x4 o[4], bf16x8 pa[2]) {
    if (domask) {
#pragma unroll
        for (int tau = 0; tau < 4; ++tau) {
            const int kb = kv0 + 32 * (tau >> 1) + 4 * (tau & 1) + 8 * g;
#pragma unroll
            for (int r = 0; r < 4; ++r)
                if (kb + r > qabs) s[tau][r] = -3e38f;
        }
    }
    float mloc = -3e38f;
#pragma unroll
    for (int tau = 0; tau < 4; ++tau)
#pragma unroll
        for (int r = 0; r < 4; ++r) mloc = fmaxf(mloc, s[tau][r]);
    mloc = fmaxf(mloc, __shfl_xor(mloc, 16));
    mloc = fmaxf(mloc, __shfl_xor(mloc, 32));
    const float mnew = fmaxf(m, mloc);
    const float fac = exp2f(m - mnew);
    m = mnew;
    float ps = 0.f;
    u16 pb[4][4];
#pragma unroll
    for (int tau = 0; tau < 4; ++tau)
#pragma unroll
        for (int r = 0; r < 4; ++r) {
            const float p = exp2f(s[tau][r] - mnew);
            ps += p;
            pb[tau][r] = f2bf(p);
        }
    ps += __shfl_xor(ps, 16);
    ps += __shfl_xor(ps, 32);
    l = l * fac + ps;
#pragma unroll
    for (int n = 0; n < 4; ++n)
#pragma unroll
        for (int r = 0; r < 4; ++r) o[n][r] *= fac;
    const u16x8 p0 = {pb[0][0], pb[0][1], pb[0][2], pb[0][3], pb[1][0], pb[1][1], pb[1][2], pb[1][3]};
    const u16x8 p1 = {pb[2][0], pb[2][1], pb[2][2], pb[2][3], pb[3][0], pb[3][1], pb[3][2], pb[3][3]};
    pa[0] = __builtin_bit_cast(bf16x8, p0);
    pa[1] = __builtin_bit_cast(bf16x8, p1);
}

__global__ __launch_bounds__(256) void k_flash(const u16* __restrict__ Qg, const u16* __restrict__ Kg,
                                               const u16* __restrict__ Vtg, u16* __restrict__ Oa) {
    __shared__ u16 sm[2][2][4096];  // [buf][K/V][64*64], swizzled content

    const int tid = threadIdx.x;
    const int lane = tid & 63;
    const int wid = tid >> 6;  // 0..3
    const int c = lane & 15, g = lane >> 4;

    const int swz = ((int)blockIdx.x & 7) * 64 + ((int)blockIdx.x >> 3);  // XCD chunking
    const int head = swz >> 5;
    const int qb = 31 - (swz & 31);  // big blocks first within each XCD
    const int q0w = qb * 128 + wid * 32;
    const int nt = 2 * qb + 2;

    const u16* Qh = Qg + head * (T_SEQ * HD);
    const u16* Kh = Kg + head * (T_SEQ * HD);
    const u16* Vh = Vtg + head * (HD * T_SEQ);

    // staging lane geometry (source pre-swizzled so linear LDS reads back swizzled)
    const int srow = lane >> 3;                              // row within 8-row chunk
    const int sxu = (((lane & 7) * 16) ^ (srow << 4)) >> 1;  // col offset, u16 units

    // Q fragments: lane holds Q[q0w+16h+c][d = dc*32 + 8g .. +7], pre-scaled by QSC
    bf16x8 qf[2][2];
#pragma unroll
    for (int h = 0; h < 2; ++h)
#pragma unroll
        for (int dc = 0; dc < 2; ++dc)
            qf[h][dc] = __builtin_bit_cast(
                bf16x8, *(const u16x8*)(Qh + (q0w + 16 * h + c) * HD + dc * 32 + 8 * g));

    f32x4 o0[4] = {}, o1[4] = {};
    float m0v = -3e38f, l0 = 0.f, m1v = -3e38f, l1 = 0.f;

    // prologue: stage tile 0 into buf 0
#pragma unroll
    for (int i = 0; i < 2; ++i) {
        const int ch = wid + 4 * i;
        gld_lds16(Kh + (ch * 8 + srow) * HD + sxu, &sm[0][0][ch * 512]);
        gld_lds16(Vh + (ch * 8 + srow) * T_SEQ + sxu, &sm[0][1][ch * 512]);
    }
    __syncthreads();

    for (int t = 0; t < nt; ++t) {
        const int cur = t & 1;
        const int kv0 = t * 64;
        if (t + 1 < nt) {  // async-stage next tile into other buffer (overlaps compute)
            const int kvn = kv0 + 64;
#pragma unroll
            for (int i = 0; i < 2; ++i) {
                const int ch = wid + 4 * i;
                gld_lds16(Kh + (kvn + ch * 8 + srow) * HD + sxu, &sm[cur ^ 1][0][ch * 512]);
                gld_lds16(Vh + (ch * 8 + srow) * T_SEQ + kvn + sxu, &sm[cur ^ 1][1][ch * 512]);
            }
        }
        if (kv0 <= q0w + 31) {
            const u16* Kl = &sm[cur][0][0];
            const u16* Vl = &sm[cur][1][0];
            f32x4 s0[4], s1[4];
#pragma unroll
            for (int tau = 0; tau < 4; ++tau) {
                const int prow = 32 * (tau >> 1) + 4 * (tau & 1) + 8 * (c >> 2) + (c & 3);
                const int sw = (prow & 7) << 4;
                const u16* kb = Kl + prow * 64;
                const bf16x8 k0 = ldfr(kb, (16 * g) ^ sw);
                const bf16x8 k1 = ldfr(kb, (64 + 16 * g) ^ sw);
                f32x4 z0 = {}, z1 = {};
                z0 = MFMA16(k0, qf[0][0], z0);
                s0[tau] = MFMA16(k1, qf[0][1], z0);
                z1 = MFMA16(k0, qf[1][0], z1);
                s1[tau] = MFMA16(k1, qf[1][1], z1);
            }
            const bool dm0 = (kv0 + 63) > (q0w);
            const bool dm1 = (kv0 + 63) > (q0w + 16);
            bf16x8 pa0[2], pa1[2];
            soft_half(s0, q0w + c, kv0, g, dm0, m0v, l0, o0, pa0);
            soft_half(s1, q0w + 16 + c, kv0, g, dm1, m1v, l1, o1, pa1);
            const int swv = (c & 7) << 4;
#pragma unroll
            for (int n = 0; n < 4; ++n) {
                const u16* vb = Vl + (n * 16 + c) * 64;
                const bf16x8 v0 = ldfr(vb, (16 * g) ^ swv);
                const bf16x8 v1 = ldfr(vb, (64 + 16 * g) ^ swv);
                o0[n] = MFMA16(v0, pa0[0], o0[n]);
                o0[n] = MFMA16(v1, pa0[1], o0[n]);
                o1[n] = MFMA16(v0, pa1[0], o1[n]);
                o1[n] = MFMA16(v1, pa1[1], o1[n]);
            }
        }
        __syncthreads();  // drains vmcnt -> buf[cur^1] staged; all reads of buf[cur] done
    }

    const float li0 = 1.0f / l0, li1 = 1.0f / l1;
#pragma unroll
    for (int n = 0; n < 4; ++n) {
        u16x4 w0, w1;
#pragma unroll
        for (int r = 0; r < 4; ++r) {
            w0[r] = f2bf(o0[n][r] * li0);
            w1[r] = f2bf(o1[n][r] * li1);
        }
        // O^T: lane holds O[q][d = n*16 + 4g + r]
        *(u16x4*)(Oa + (q0w + c) * C_DIM + head * HD + n * 16 + 4 * g) = w0;
        *(u16x4*)(Oa + (q0w + 16 + c) * C_DIM + head * HD + n * 16 + 4 * g) = w1;
    }
}

// ---------------- launch ----------------

extern "C" void kernel_launch(void* const* d_in, const int* in_sizes, int n_in,
                              void* d_out, int out_size, void* d_ws, size_t ws_size,
                              hipStream_t stream) {
    const float* x      = (const float*)d_in[0];
    const float* W_attn = (const float*)d_in[1];
    const float* b_attn = (const float*)d_in[2];
    const float* W_proj = (const float*)d_in[3];
    const float* b_proj = (const float*)d_in[4];
    float* out = (float*)d_out;

    char* ws = (char*)d_ws;
    u16* xb  = (u16*)(ws);                // 8 MB  x bf16 [4096][1024]
    u16* Wat = (u16*)(ws + (8u << 20));   // 6 MB  W_attn^T bf16 [3072][1024]
    u16* Wpt = (u16*)(ws + (14u << 20));  // 2 MB  W_proj^T bf16 [1024][1024]
    u16* Qb  = (u16*)(ws + (16u << 20));  // 8 MB  Q (pre-scaled) [16][4096][64]
    u16* Kb  = (u16*)(ws + (24u << 20));  // 8 MB  K [16][4096][64]
    u16* Vtb = (u16*)(ws + (32u << 20));  // 8 MB  V^T [16][64][4096]
    u16* Ab  = (u16*)(ws + (40u << 20));  // 8 MB  attn out bf16 [4096][1024]

    k_cvt_x<<<2048, 256, 0, stream>>>(x, xb);
    k_transpose_w<<<dim3(96, 32), dim3(32, 8), 0, stream>>>(W_attn, Wat, 1024, 3072);
    k_transpose_w<<<dim3(32, 32), dim3(32, 8), 0, stream>>>(W_proj, Wpt, 1024, 1024);
    k_gemm<0><<<768, 256, 0, stream>>>(xb, Wat, b_attn, Qb, Kb, Vtb, nullptr, 1024, 32);
    k_flash<<<512, 256, 0, stream>>>(Qb, Kb, Vtb, Ab);
    k_gemm<1><<<256, 256, 0, stream>>>(Ab, Wpt, b_proj, nullptr, nullptr, nullptr, out, 1024, 32);
}

// Round 3
// 194.757 us; speedup vs baseline: 2.2706x; 1.2086x over previous
//
#include <hip/hip_runtime.h>
#include <hip/hip_bf16.h>

// GPT-2 attention block, MI355X. B=1 T=4096 C=1024 H=16 D=64.
// R3: flash rebalanced: 64q blocks (2 waves x 32q), 1024 blocks = 4/CU resident,
//     qb-pairing for per-CU balance, head-per-XCD L2 locality, defer-max (T13),
//     setprio around MFMA (T5). GEMMs unchanged from R2 (verified).

typedef unsigned short u16;
typedef u16 u16x4 __attribute__((ext_vector_type(4)));
typedef u16 u16x8 __attribute__((ext_vector_type(8)));
typedef __bf16 bf16x8 __attribute__((ext_vector_type(8)));
typedef float f32x4 __attribute__((ext_vector_type(4)));

#define T_SEQ 4096
#define C_DIM 1024
#define NH 16
#define HD 64
#define QSC 0.18033688f  // 0.125 * log2(e): folded into Q at QKV epilogue

static __device__ __forceinline__ u16 f2bf(float f) {
    __hip_bfloat16 h = __float2bfloat16(f);
    return __builtin_bit_cast(u16, h);
}

// 16B LDS read at byte offset (must be 16B aligned)
static __device__ __forceinline__ bf16x8 ldfr(const u16* base, int byteoff) {
    return __builtin_bit_cast(bf16x8, *(const u16x8*)(base + (byteoff >> 1)));
}

// async global->LDS, 16B per lane; LDS dest = wave-uniform base + lane*16
static __device__ __forceinline__ void gld_lds16(const void* g, void* l) {
    __builtin_amdgcn_global_load_lds((const __attribute__((address_space(1))) void*)g,
                                     (__attribute__((address_space(3))) void*)l, 16, 0, 0);
}

#define MFMA16(a, b, c) __builtin_amdgcn_mfma_f32_16x16x32_bf16((a), (b), (c), 0, 0, 0)

// ---------------- prep kernels ----------------

__global__ __launch_bounds__(256) void k_cvt_x(const float* __restrict__ x, u16* __restrict__ xb) {
    int i = (blockIdx.x * 256 + threadIdx.x) * 8;
    float4 a = *(const float4*)(x + i);
    float4 b = *(const float4*)(x + i + 4);
    u16x8 o;
    o[0] = f2bf(a.x); o[1] = f2bf(a.y); o[2] = f2bf(a.z); o[3] = f2bf(a.w);
    o[4] = f2bf(b.x); o[5] = f2bf(b.y); o[6] = f2bf(b.z); o[7] = f2bf(b.w);
    *(u16x8*)(xb + i) = o;
}

// src [R][Cc] f32 -> dst [Cc][R] bf16
__global__ __launch_bounds__(256) void k_transpose_w(const float* __restrict__ src,
                                                     u16* __restrict__ dst, int R, int Cc) {
    __shared__ float tile[32][33];
    int bx = blockIdx.x * 32;
    int by = blockIdx.y * 32;
    int x = threadIdx.x, y = threadIdx.y;
#pragma unroll
    for (int i = 0; i < 32; i += 8)
        tile[y + i][x] = src[(by + y + i) * Cc + bx + x];
    __syncthreads();
#pragma unroll
    for (int i = 0; i < 32; i += 8)
        dst[(bx + y + i) * R + by + x] = f2bf(tile[x][y + i]);
}

// ---------------- GEMM: C[m][n] = sum_k A[m][k]*Bt[n][k] + bias[n] ----------------
// 128x128 tile, BK=64, 4 waves (2x2), gload_lds staging with pre-swizzled source,
// contiguous-k frags (lane reads k=8g..8g+7 as one b128; both operands use same perm).

template <int EPI>
__global__ __launch_bounds__(256) void k_gemm(const u16* __restrict__ A, const u16* __restrict__ Bt,
                                              const float* __restrict__ bias,
                                              u16* __restrict__ outQ, u16* __restrict__ outK,
                                              u16* __restrict__ outVt, float* __restrict__ outF,
                                              int kd, int nbx) {
    __shared__ u16 Al[128 * 64];
    __shared__ u16 Bl[128 * 64];
    const int tid = threadIdx.x;
    const int lane = tid & 63;
    const int wid = tid >> 6;
    const int wm = wid >> 1, wn = wid & 1;
    const int c = lane & 15, g = lane >> 4;
    const int nwg = gridDim.x;
    const int swzb = ((int)blockIdx.x & 7) * (nwg >> 3) + ((int)blockIdx.x >> 3);
    const int m0 = (swzb % nbx) * 128;
    const int n0 = (swzb / nbx) * 128;
    const int srow = lane >> 3;
    const int sxu = (((lane & 7) * 16) ^ (srow << 4)) >> 1;  // pre-swizzled src col (u16)
    const int swa = (c & 7) << 4;                            // read-side swizzle key

    f32x4 acc[4][4] = {};

    for (int k0 = 0; k0 < kd; k0 += 64) {
#pragma unroll
        for (int i = 0; i < 4; ++i) {
            const int ch = wid * 4 + i;
            const int row = ch * 8 + srow;
            gld_lds16(A + (m0 + row) * kd + k0 + sxu, &Al[ch * 512]);
            gld_lds16(Bt + (n0 + row) * kd + k0 + sxu, &Bl[ch * 512]);
        }
        __syncthreads();
        bf16x8 af[4][2], bfm[4][2];
#pragma unroll
        for (int mi = 0; mi < 4; ++mi) {
            const u16* p = Al + (wm * 64 + mi * 16 + c) * 64;
            af[mi][0] = ldfr(p, (16 * g) ^ swa);
            af[mi][1] = ldfr(p, (64 + 16 * g) ^ swa);
        }
#pragma unroll
        for (int ni = 0; ni < 4; ++ni) {
            const u16* p = Bl + (wn * 64 + ni * 16 + c) * 64;
            bfm[ni][0] = ldfr(p, (16 * g) ^ swa);
            bfm[ni][1] = ldfr(p, (64 + 16 * g) ^ swa);
        }
#pragma unroll
        for (int mi = 0; mi < 4; ++mi)
#pragma unroll
            for (int ni = 0; ni < 4; ++ni) {
                acc[mi][ni] = MFMA16(af[mi][0], bfm[ni][0], acc[mi][ni]);
                acc[mi][ni] = MFMA16(af[mi][1], bfm[ni][1], acc[mi][ni]);
            }
        __syncthreads();
    }

    // C/D: lane(16g+c) reg r -> row = 4g+r, col = c
    const int mbase = m0 + wm * 64;
    const int nbase = n0 + wn * 64;
    if (EPI == 0) {
#pragma unroll
        for (int ni = 0; ni < 4; ++ni) {
            const int n = nbase + ni * 16 + c;
            const float bv = bias[n];
            const int part = n >> 10;  // 0=Q 1=K 2=V (uniform per block)
            const int nr = n & 1023;
            const int h = nr >> 6, d = nr & 63;
#pragma unroll
            for (int mi = 0; mi < 4; ++mi) {
                const int mrow = mbase + mi * 16 + g * 4;
                if (part == 2) {
                    u16x4 pk;
#pragma unroll
                    for (int r = 0; r < 4; ++r) pk[r] = f2bf(acc[mi][ni][r] + bv);
                    *(u16x4*)(outVt + (h * HD + d) * T_SEQ + mrow) = pk;  // V^T: [h][d][t]
                } else if (part == 1) {
                    u16* dst = outK + h * T_SEQ * HD + d;
#pragma unroll
                    for (int r = 0; r < 4; ++r) dst[(mrow + r) * HD] = f2bf(acc[mi][ni][r] + bv);
                } else {
                    u16* dst = outQ + h * T_SEQ * HD + d;
#pragma unroll
                    for (int r = 0; r < 4; ++r) dst[(mrow + r) * HD] = f2bf((acc[mi][ni][r] + bv) * QSC);
                }
            }
        }
    } else {
#pragma unroll
        for (int ni = 0; ni < 4; ++ni) {
            const int n = nbase + ni * 16 + c;
            const float bv = bias[n];
#pragma unroll
            for (int mi = 0; mi < 4; ++mi) {
                const int mrow = mbase + mi * 16 + g * 4;
#pragma unroll
                for (int r = 0; r < 4; ++r)
                    outF[(mrow + r) * C_DIM + n] = acc[mi][ni][r] + bv;
            }
        }
    }
}

// ---------------- flash attention ----------------
// 2 waves/block, 64 q-rows (32 per wave, 2 halves of 16). KV tile 64, double-buffered LDS.
// Swapped QK^T with contiguous-k perm; lane(16g+c) holds P[q=c][kv=32ks+8g..+7] in regs
// -> feeds PV B-operand directly. PV: O^T = mfma(V^T, P); softmax state lane-local.
// Defer-max: skip O/l rescale while __all(mloc <= m + 8) (P bounded by 2^8).

static __device__ __forceinline__ void soft_half(f32x4 s[4], int qabs, int kv0, int g,
                                                 bool domask, float& m, float& l,
                                                 f32x4 o[4], bf16x8 pa[2]) {
    if (domask) {
#pragma unroll
        for (int tau = 0; tau < 4; ++tau) {
            const int kb = kv0 + 32 * (tau >> 1) + 4 * (tau & 1) + 8 * g;
#pragma unroll
            for (int r = 0; r < 4; ++r)
                if (kb + r > qabs) s[tau][r] = -3e38f;
        }
    }
    float mx01 = fmaxf(fmaxf(s[0][0], s[0][1]), fmaxf(s[0][2], s[0][3]));
    float mx23 = fmaxf(fmaxf(s[1][0], s[1][1]), fmaxf(s[1][2], s[1][3]));
    float mx45 = fmaxf(fmaxf(s[2][0], s[2][1]), fmaxf(s[2][2], s[2][3]));
    float mx67 = fmaxf(fmaxf(s[3][0], s[3][1]), fmaxf(s[3][2], s[3][3]));
    float mloc = fmaxf(fmaxf(mx01, mx23), fmaxf(mx45, mx67));
    mloc = fmaxf(mloc, __shfl_xor(mloc, 16));
    mloc = fmaxf(mloc, __shfl_xor(mloc, 32));
    if (!__all(mloc <= m + 8.0f)) {  // wave-uniform rescale (T13 defer-max)
        const float mnew = fmaxf(m, mloc);
        const float fac = exp2f(m - mnew);
        m = mnew;
        l *= fac;
#pragma unroll
        for (int n = 0; n < 4; ++n)
#pragma unroll
            for (int r = 0; r < 4; ++r) o[n][r] *= fac;
    }
    float ps = 0.f;
    u16 pb[4][4];
#pragma unroll
    for (int tau = 0; tau < 4; ++tau)
#pragma unroll
        for (int r = 0; r < 4; ++r) {
            const float p = exp2f(s[tau][r] - m);
            ps += p;
            pb[tau][r] = f2bf(p);
        }
    ps += __shfl_xor(ps, 16);
    ps += __shfl_xor(ps, 32);
    l += ps;
    const u16x8 p0 = {pb[0][0], pb[0][1], pb[0][2], pb[0][3], pb[1][0], pb[1][1], pb[1][2], pb[1][3]};
    const u16x8 p1 = {pb[2][0], pb[2][1], pb[2][2], pb[2][3], pb[3][0], pb[3][1], pb[3][2], pb[3][3]};
    pa[0] = __builtin_bit_cast(bf16x8, p0);
    pa[1] = __builtin_bit_cast(bf16x8, p1);
}

__global__ __launch_bounds__(128) void k_flash(const u16* __restrict__ Qg, const u16* __restrict__ Kg,
                                               const u16* __restrict__ Vtg, u16* __restrict__ Oa) {
    __shared__ u16 sm[2][2][4096];  // [buf][K/V][64*64], swizzled content

    const int tid = threadIdx.x;
    const int lane = tid & 63;
    const int wid = tid >> 6;  // 0..1
    const int c = lane & 15, g = lane >> 4;

    // work mapping: XCD b&7 owns heads 2x..2x+1 (K+V 2MB fits 4MB XCD L2);
    // qb paired (jj, 95-jj) so co-resident blocks sum to ~constant work.
    const int b = blockIdx.x;        // 0..1023
    const int j = b >> 3;            // 0..127 within XCD
    const int head = (b & 7) * 2 + (j >> 6);
    const int jj = j & 63;
    const int qb = (jj < 32) ? jj : 95 - jj;  // 0..63
    const int q0w = qb * 64 + wid * 32;
    const int nt = qb + 1;  // kv tiles of 64

    const u16* Qh = Qg + head * (T_SEQ * HD);
    const u16* Kh = Kg + head * (T_SEQ * HD);
    const u16* Vh = Vtg + head * (HD * T_SEQ);

    // staging lane geometry (source pre-swizzled so linear LDS reads back swizzled)
    const int srow = lane >> 3;                              // row within 8-row chunk
    const int sxu = (((lane & 7) * 16) ^ (srow << 4)) >> 1;  // col offset, u16 units

    // Q fragments: lane holds Q[q0w+16h+c][d = dc*32 + 8g .. +7], pre-scaled by QSC
    bf16x8 qf[2][2];
#pragma unroll
    for (int h = 0; h < 2; ++h)
#pragma unroll
        for (int dc = 0; dc < 2; ++dc)
            qf[h][dc] = __builtin_bit_cast(
                bf16x8, *(const u16x8*)(Qh + (q0w + 16 * h + c) * HD + dc * 32 + 8 * g));

    f32x4 o0[4] = {}, o1[4] = {};
    float m0v = -3e38f, l0 = 0.f, m1v = -3e38f, l1 = 0.f;

    // prologue: stage tile 0 into buf 0 (wave w: chunks w*4..w*4+3 of K and V)
#pragma unroll
    for (int i = 0; i < 4; ++i) {
        const int ch = wid * 4 + i;
        gld_lds16(Kh + (ch * 8 + srow) * HD + sxu, &sm[0][0][ch * 512]);
        gld_lds16(Vh + (ch * 8 + srow) * T_SEQ + sxu, &sm[0][1][ch * 512]);
    }
    __syncthreads();

    for (int t = 0; t < nt; ++t) {
        const int cur = t & 1;
        const int kv0 = t * 64;
        if (t + 1 < nt) {  // async-stage next tile (overlaps compute; drained at barrier)
            const int kvn = kv0 + 64;
#pragma unroll
            for (int i = 0; i < 4; ++i) {
                const int ch = wid * 4 + i;
                gld_lds16(Kh + (kvn + ch * 8 + srow) * HD + sxu, &sm[cur ^ 1][0][ch * 512]);
                gld_lds16(Vh + (ch * 8 + srow) * T_SEQ + kvn + sxu, &sm[cur ^ 1][1][ch * 512]);
            }
        }
        {
            const u16* Kl = &sm[cur][0][0];
            const u16* Vl = &sm[cur][1][0];
            f32x4 s0[4], s1[4];
            __builtin_amdgcn_s_setprio(1);
#pragma unroll
            for (int tau = 0; tau < 4; ++tau) {
                const int prow = 32 * (tau >> 1) + 4 * (tau & 1) + 8 * (c >> 2) + (c & 3);
                const int sw = (prow & 7) << 4;
                const u16* kb = Kl + prow * 64;
                const bf16x8 k0 = ldfr(kb, (16 * g) ^ sw);
                const bf16x8 k1 = ldfr(kb, (64 + 16 * g) ^ sw);
                f32x4 z0 = {}, z1 = {};
                z0 = MFMA16(k0, qf[0][0], z0);
                s0[tau] = MFMA16(k1, qf[0][1], z0);
                z1 = MFMA16(k0, qf[1][0], z1);
                s1[tau] = MFMA16(k1, qf[1][1], z1);
            }
            __builtin_amdgcn_s_setprio(0);
            const bool dm0 = (kv0 + 63) > (q0w);
            const bool dm1 = (kv0 + 63) > (q0w + 16);
            bf16x8 pa0[2], pa1[2];
            soft_half(s0, q0w + c, kv0, g, dm0, m0v, l0, o0, pa0);
            soft_half(s1, q0w + 16 + c, kv0, g, dm1, m1v, l1, o1, pa1);
            const int swv = (c & 7) << 4;
            __builtin_amdgcn_s_setprio(1);
#pragma unroll
            for (int n = 0; n < 4; ++n) {
                const u16* vb = Vl + (n * 16 + c) * 64;
                const bf16x8 v0 = ldfr(vb, (16 * g) ^ swv);
                const bf16x8 v1 = ldfr(vb, (64 + 16 * g) ^ swv);
                o0[n] = MFMA16(v0, pa0[0], o0[n]);
                o0[n] = MFMA16(v1, pa0[1], o0[n]);
                o1[n] = MFMA16(v0, pa1[0], o1[n]);
                o1[n] = MFMA16(v1, pa1[1], o1[n]);
            }
            __builtin_amdgcn_s_setprio(0);
        }
        __syncthreads();  // drains vmcnt -> buf[cur^1] staged; all reads of buf[cur] done
    }

    const float li0 = 1.0f / l0, li1 = 1.0f / l1;
#pragma unroll
    for (int n = 0; n < 4; ++n) {
        u16x4 w0, w1;
#pragma unroll
        for (int r = 0; r < 4; ++r) {
            w0[r] = f2bf(o0[n][r] * li0);
            w1[r] = f2bf(o1[n][r] * li1);
        }
        // O^T: lane holds O[q][d = n*16 + 4g + r]
        *(u16x4*)(Oa + (q0w + c) * C_DIM + head * HD + n * 16 + 4 * g) = w0;
        *(u16x4*)(Oa + (q0w + 16 + c) * C_DIM + head * HD + n * 16 + 4 * g) = w1;
    }
}

// ---------------- launch ----------------

extern "C" void kernel_launch(void* const* d_in, const int* in_sizes, int n_in,
                              void* d_out, int out_size, void* d_ws, size_t ws_size,
                              hipStream_t stream) {
    const float* x      = (const float*)d_in[0];
    const float* W_attn = (const float*)d_in[1];
    const float* b_attn = (const float*)d_in[2];
    const float* W_proj = (const float*)d_in[3];
    const float* b_proj = (const float*)d_in[4];
    float* out = (float*)d_out;

    char* ws = (char*)d_ws;
    u16* xb  = (u16*)(ws);                // 8 MB  x bf16 [4096][1024]
    u16* Wat = (u16*)(ws + (8u << 20));   // 6 MB  W_attn^T bf16 [3072][1024]
    u16* Wpt = (u16*)(ws + (14u << 20));  // 2 MB  W_proj^T bf16 [1024][1024]
    u16* Qb  = (u16*)(ws + (16u << 20));  // 8 MB  Q (pre-scaled) [16][4096][64]
    u16* Kb  = (u16*)(ws + (24u << 20));  // 8 MB  K [16][4096][64]
    u16* Vtb = (u16*)(ws + (32u << 20));  // 8 MB  V^T [16][64][4096]
    u16* Ab  = (u16*)(ws + (40u << 20));  // 8 MB  attn out bf16 [4096][1024]

    k_cvt_x<<<2048, 256, 0, stream>>>(x, xb);
    k_transpose_w<<<dim3(96, 32), dim3(32, 8), 0, stream>>>(W_attn, Wat, 1024, 3072);
    k_transpose_w<<<dim3(32, 32), dim3(32, 8), 0, stream>>>(W_proj, Wpt, 1024, 1024);
    k_gemm<0><<<768, 256, 0, stream>>>(xb, Wat, b_attn, Qb, Kb, Vtb, nullptr, 1024, 32);
    k_flash<<<1024, 128, 0, stream>>>(Qb, Kb, Vtb, Ab);
    k_gemm<1><<<256, 256, 0, stream>>>(Ab, Wpt, b_proj, nullptr, nullptr, nullptr, out, 1024, 32);
}

// Round 4
// 173.118 us; speedup vs baseline: 2.5544x; 1.1250x over previous
//
#include <hip/hip_runtime.h>
#include <hip/hip_bf16.h>

// GPT-2 attention block, MI355X. B=1 T=4096 C=1024 H=16 D=64.
// R4: flash = persistent blocks + atomic LPT job queue (perfect balance without
//     relying on undefined block->CU mapping); fixed-max softmax (m=0: p=exp2(s),
//     safe: folded scores |s|<~4, diagonal guarantees row-max>=0); l accumulated
//     via ones-MFMA (no shuffles/adds on VALU). GEMMs unchanged (verified).

typedef unsigned short u16;
typedef u16 u16x4 __attribute__((ext_vector_type(4)));
typedef u16 u16x8 __attribute__((ext_vector_type(8)));
typedef __bf16 bf16x8 __attribute__((ext_vector_type(8)));
typedef float f32x4 __attribute__((ext_vector_type(4)));

#define T_SEQ 4096
#define C_DIM 1024
#define NH 16
#define HD 64
#define QSC 0.18033688f  // 0.125 * log2(e): folded into Q at QKV epilogue

static __device__ __forceinline__ u16 f2bf(float f) {
    __hip_bfloat16 h = __float2bfloat16(f);
    return __builtin_bit_cast(u16, h);
}

// 16B LDS read at byte offset (must be 16B aligned)
static __device__ __forceinline__ bf16x8 ldfr(const u16* base, int byteoff) {
    return __builtin_bit_cast(bf16x8, *(const u16x8*)(base + (byteoff >> 1)));
}

// async global->LDS, 16B per lane; LDS dest = wave-uniform base + lane*16
static __device__ __forceinline__ void gld_lds16(const void* g, void* l) {
    __builtin_amdgcn_global_load_lds((const __attribute__((address_space(1))) void*)g,
                                     (__attribute__((address_space(3))) void*)l, 16, 0, 0);
}

#define MFMA16(a, b, c) __builtin_amdgcn_mfma_f32_16x16x32_bf16((a), (b), (c), 0, 0, 0)

// ---------------- prep kernels ----------------

__global__ __launch_bounds__(256) void k_cvt_x(const float* __restrict__ x, u16* __restrict__ xb) {
    int i = (blockIdx.x * 256 + threadIdx.x) * 8;
    float4 a = *(const float4*)(x + i);
    float4 b = *(const float4*)(x + i + 4);
    u16x8 o;
    o[0] = f2bf(a.x); o[1] = f2bf(a.y); o[2] = f2bf(a.z); o[3] = f2bf(a.w);
    o[4] = f2bf(b.x); o[5] = f2bf(b.y); o[6] = f2bf(b.z); o[7] = f2bf(b.w);
    *(u16x8*)(xb + i) = o;
}

// src [R][Cc] f32 -> dst [Cc][R] bf16
__global__ __launch_bounds__(256) void k_transpose_w(const float* __restrict__ src,
                                                     u16* __restrict__ dst, int R, int Cc) {
    __shared__ float tile[32][33];
    int bx = blockIdx.x * 32;
    int by = blockIdx.y * 32;
    int x = threadIdx.x, y = threadIdx.y;
#pragma unroll
    for (int i = 0; i < 32; i += 8)
        tile[y + i][x] = src[(by + y + i) * Cc + bx + x];
    __syncthreads();
#pragma unroll
    for (int i = 0; i < 32; i += 8)
        dst[(bx + y + i) * R + by + x] = f2bf(tile[x][y + i]);
}

// ---------------- GEMM: C[m][n] = sum_k A[m][k]*Bt[n][k] + bias[n] ----------------
// 128x128 tile, BK=64, 4 waves (2x2), gload_lds staging with pre-swizzled source,
// contiguous-k frags (lane reads k=8g..8g+7 as one b128; both operands use same perm).

template <int EPI>
__global__ __launch_bounds__(256) void k_gemm(const u16* __restrict__ A, const u16* __restrict__ Bt,
                                              const float* __restrict__ bias,
                                              u16* __restrict__ outQ, u16* __restrict__ outK,
                                              u16* __restrict__ outVt, float* __restrict__ outF,
                                              int kd, int nbx) {
    __shared__ u16 Al[128 * 64];
    __shared__ u16 Bl[128 * 64];
    const int tid = threadIdx.x;
    const int lane = tid & 63;
    const int wid = tid >> 6;
    const int wm = wid >> 1, wn = wid & 1;
    const int c = lane & 15, g = lane >> 4;
    const int nwg = gridDim.x;
    const int swzb = ((int)blockIdx.x & 7) * (nwg >> 3) + ((int)blockIdx.x >> 3);
    const int m0 = (swzb % nbx) * 128;
    const int n0 = (swzb / nbx) * 128;
    const int srow = lane >> 3;
    const int sxu = (((lane & 7) * 16) ^ (srow << 4)) >> 1;  // pre-swizzled src col (u16)
    const int swa = (c & 7) << 4;                            // read-side swizzle key

    f32x4 acc[4][4] = {};

    for (int k0 = 0; k0 < kd; k0 += 64) {
#pragma unroll
        for (int i = 0; i < 4; ++i) {
            const int ch = wid * 4 + i;
            const int row = ch * 8 + srow;
            gld_lds16(A + (m0 + row) * kd + k0 + sxu, &Al[ch * 512]);
            gld_lds16(Bt + (n0 + row) * kd + k0 + sxu, &Bl[ch * 512]);
        }
        __syncthreads();
        bf16x8 af[4][2], bfm[4][2];
#pragma unroll
        for (int mi = 0; mi < 4; ++mi) {
            const u16* p = Al + (wm * 64 + mi * 16 + c) * 64;
            af[mi][0] = ldfr(p, (16 * g) ^ swa);
            af[mi][1] = ldfr(p, (64 + 16 * g) ^ swa);
        }
#pragma unroll
        for (int ni = 0; ni < 4; ++ni) {
            const u16* p = Bl + (wn * 64 + ni * 16 + c) * 64;
            bfm[ni][0] = ldfr(p, (16 * g) ^ swa);
            bfm[ni][1] = ldfr(p, (64 + 16 * g) ^ swa);
        }
#pragma unroll
        for (int mi = 0; mi < 4; ++mi)
#pragma unroll
            for (int ni = 0; ni < 4; ++ni) {
                acc[mi][ni] = MFMA16(af[mi][0], bfm[ni][0], acc[mi][ni]);
                acc[mi][ni] = MFMA16(af[mi][1], bfm[ni][1], acc[mi][ni]);
            }
        __syncthreads();
    }

    // C/D: lane(16g+c) reg r -> row = 4g+r, col = c
    const int mbase = m0 + wm * 64;
    const int nbase = n0 + wn * 64;
    if (EPI == 0) {
#pragma unroll
        for (int ni = 0; ni < 4; ++ni) {
            const int n = nbase + ni * 16 + c;
            const float bv = bias[n];
            const int part = n >> 10;  // 0=Q 1=K 2=V (uniform per block)
            const int nr = n & 1023;
            const int h = nr >> 6, d = nr & 63;
#pragma unroll
            for (int mi = 0; mi < 4; ++mi) {
                const int mrow = mbase + mi * 16 + g * 4;
                if (part == 2) {
                    u16x4 pk;
#pragma unroll
                    for (int r = 0; r < 4; ++r) pk[r] = f2bf(acc[mi][ni][r] + bv);
                    *(u16x4*)(outVt + (h * HD + d) * T_SEQ + mrow) = pk;  // V^T: [h][d][t]
                } else if (part == 1) {
                    u16* dst = outK + h * T_SEQ * HD + d;
#pragma unroll
                    for (int r = 0; r < 4; ++r) dst[(mrow + r) * HD] = f2bf(acc[mi][ni][r] + bv);
                } else {
                    u16* dst = outQ + h * T_SEQ * HD + d;
#pragma unroll
                    for (int r = 0; r < 4; ++r) dst[(mrow + r) * HD] = f2bf((acc[mi][ni][r] + bv) * QSC);
                }
            }
        }
    } else {
#pragma unroll
        for (int ni = 0; ni < 4; ++ni) {
            const int n = nbase + ni * 16 + c;
            const float bv = bias[n];
#pragma unroll
            for (int mi = 0; mi < 4; ++mi) {
                const int mrow = mbase + mi * 16 + g * 4;
#pragma unroll
                for (int r = 0; r < 4; ++r)
                    outF[(mrow + r) * C_DIM + n] = acc[mi][ni][r] + bv;
            }
        }
    }
}

// ---------------- flash attention ----------------
// Persistent 2-wave blocks popping jobs (head, qb) from an atomic queue, LPT order
// (qb descending) -> near-perfect balance independent of block->CU mapping.
// Per job: 64 q rows (32/wave), kv tiles of 64, double-buffered swizzled LDS.
// Swapped QK^T (contiguous-k perm); lane(16g+c) holds P[q=c][kv=32ks+8g..+7] in regs.
// Fixed-max softmax: folded scores |s|<~4 (std 0.6) and diagonal guarantees row-max>=0,
// so p = exp2(s) directly (no running max, no rescale); exact after final O/l.
// l = sum_k P via ones-A MFMA: every lane gets l(q=c) in all acc regs.

static __device__ __forceinline__ void p_gen(f32x4 s[4], int qabs, int kv0, int g,
                                             bool domask, bf16x8 pa[2]) {
    if (domask) {
#pragma unroll
        for (int tau = 0; tau < 4; ++tau) {
            const int kb = kv0 + 32 * (tau >> 1) + 4 * (tau & 1) + 8 * g;
#pragma unroll
            for (int r = 0; r < 4; ++r)
                if (kb + r > qabs) s[tau][r] = -3e38f;
        }
    }
    u16 pb[4][4];
#pragma unroll
    for (int tau = 0; tau < 4; ++tau)
#pragma unroll
        for (int r = 0; r < 4; ++r)
            pb[tau][r] = f2bf(__builtin_amdgcn_exp2f(s[tau][r]));  // exp2(-3e38)=0
    const u16x8 p0 = {pb[0][0], pb[0][1], pb[0][2], pb[0][3], pb[1][0], pb[1][1], pb[1][2], pb[1][3]};
    const u16x8 p1 = {pb[2][0], pb[2][1], pb[2][2], pb[2][3], pb[3][0], pb[3][1], pb[3][2], pb[3][3]};
    pa[0] = __builtin_bit_cast(bf16x8, p0);
    pa[1] = __builtin_bit_cast(bf16x8, p1);
}

__global__ __launch_bounds__(128) void k_flash(const u16* __restrict__ Qg, const u16* __restrict__ Kg,
                                               const u16* __restrict__ Vtg, u16* __restrict__ Oa,
                                               unsigned* __restrict__ cnt) {
    __shared__ u16 sm[2][2][4096];  // [buf][K/V][64*64], swizzled content
    volatile unsigned* jw = (volatile unsigned*)&sm[0][0][0];  // job broadcast slot (overlaid)

    const int tid = threadIdx.x;
    const int lane = tid & 63;
    const int wid = tid >> 6;  // 0..1
    const int c = lane & 15, g = lane >> 4;
    const int srow = lane >> 3;                              // staging row within 8-row chunk
    const int sxu = (((lane & 7) * 16) ^ (srow << 4)) >> 1;  // pre-swizzled src col (u16)

    const u16x8 onespat = {0x3F80, 0x3F80, 0x3F80, 0x3F80, 0x3F80, 0x3F80, 0x3F80, 0x3F80};
    const bf16x8 onesf = __builtin_bit_cast(bf16x8, onespat);  // bf16 1.0 x8

    for (;;) {
        if (tid == 0) *jw = atomicAdd(cnt, 1u);
        __syncthreads();                 // publish job id
        const unsigned j = *jw;
        __syncthreads();                 // protect jw before staging overwrites sm[0]
        if (j >= 1024u) break;

        const int qb = 63 - (int)(j >> 4);  // LPT: largest jobs first
        const int head = (int)(j & 15u);
        const int q0w = qb * 64 + wid * 32;
        const int nt = qb + 1;  // kv tiles of 64

        const u16* Qh = Qg + head * (T_SEQ * HD);
        const u16* Kh = Kg + head * (T_SEQ * HD);
        const u16* Vh = Vtg + head * (HD * T_SEQ);

        // Q fragments: lane holds Q[q0w+16h+c][d = dc*32 + 8g .. +7], pre-scaled by QSC
        bf16x8 qf[2][2];
#pragma unroll
        for (int h = 0; h < 2; ++h)
#pragma unroll
            for (int dc = 0; dc < 2; ++dc)
                qf[h][dc] = __builtin_bit_cast(
                    bf16x8, *(const u16x8*)(Qh + (q0w + 16 * h + c) * HD + dc * 32 + 8 * g));

        f32x4 o0[4] = {}, o1[4] = {}, ol0 = {}, ol1 = {};

        // prologue: stage tile 0 into buf 0 (wave w: chunks w*4..w*4+3 of K and V)
#pragma unroll
        for (int i = 0; i < 4; ++i) {
            const int ch = wid * 4 + i;
            gld_lds16(Kh + (ch * 8 + srow) * HD + sxu, &sm[0][0][ch * 512]);
            gld_lds16(Vh + (ch * 8 + srow) * T_SEQ + sxu, &sm[0][1][ch * 512]);
        }
        __syncthreads();

        for (int t = 0; t < nt; ++t) {
            const int cur = t & 1;
            const int kv0 = t * 64;
            if (t + 1 < nt) {  // async-stage next tile (overlaps compute; drained at barrier)
                const int kvn = kv0 + 64;
#pragma unroll
                for (int i = 0; i < 4; ++i) {
                    const int ch = wid * 4 + i;
                    gld_lds16(Kh + (kvn + ch * 8 + srow) * HD + sxu, &sm[cur ^ 1][0][ch * 512]);
                    gld_lds16(Vh + (ch * 8 + srow) * T_SEQ + kvn + sxu, &sm[cur ^ 1][1][ch * 512]);
                }
            }
            const u16* Kl = &sm[cur][0][0];
            const u16* Vl = &sm[cur][1][0];
            f32x4 s0[4], s1[4];
            __builtin_amdgcn_s_setprio(1);
#pragma unroll
            for (int tau = 0; tau < 4; ++tau) {
                const int prow = 32 * (tau >> 1) + 4 * (tau & 1) + 8 * (c >> 2) + (c & 3);
                const int sw = (prow & 7) << 4;
                const u16* kb = Kl + prow * 64;
                const bf16x8 k0 = ldfr(kb, (16 * g) ^ sw);
                const bf16x8 k1 = ldfr(kb, (64 + 16 * g) ^ sw);
                f32x4 z0 = {}, z1 = {};
                z0 = MFMA16(k0, qf[0][0], z0);
                s0[tau] = MFMA16(k1, qf[0][1], z0);
                z1 = MFMA16(k0, qf[1][0], z1);
                s1[tau] = MFMA16(k1, qf[1][1], z1);
            }
            __builtin_amdgcn_s_setprio(0);
            const bool dm0 = (kv0 + 63) > (q0w);
            const bool dm1 = (kv0 + 63) > (q0w + 16);
            bf16x8 pa0[2], pa1[2];
            p_gen(s0, q0w + c, kv0, g, dm0, pa0);
            p_gen(s1, q0w + 16 + c, kv0, g, dm1, pa1);
            const int swv = (c & 7) << 4;
            __builtin_amdgcn_s_setprio(1);
#pragma unroll
            for (int n = 0; n < 4; ++n) {
                const u16* vb = Vl + (n * 16 + c) * 64;
                const bf16x8 v0 = ldfr(vb, (16 * g) ^ swv);
                const bf16x8 v1 = ldfr(vb, (64 + 16 * g) ^ swv);
                o0[n] = MFMA16(v0, pa0[0], o0[n]);
                o0[n] = MFMA16(v1, pa0[1], o0[n]);
                o1[n] = MFMA16(v0, pa1[0], o1[n]);
                o1[n] = MFMA16(v1, pa1[1], o1[n]);
            }
            // l = sum_k P : ones-A MFMA; every lane gets l(q=c) in all 4 regs
            ol0 = MFMA16(onesf, pa0[0], ol0);
            ol0 = MFMA16(onesf, pa0[1], ol0);
            ol1 = MFMA16(onesf, pa1[0], ol1);
            ol1 = MFMA16(onesf, pa1[1], ol1);
            __builtin_amdgcn_s_setprio(0);
            __syncthreads();  // drains vmcnt -> buf[cur^1] staged; reads of buf[cur] done
        }

        const float li0 = 1.0f / ol0[0], li1 = 1.0f / ol1[0];
#pragma unroll
        for (int n = 0; n < 4; ++n) {
            u16x4 w0, w1;
#pragma unroll
            for (int r = 0; r < 4; ++r) {
                w0[r] = f2bf(o0[n][r] * li0);
                w1[r] = f2bf(o1[n][r] * li1);
            }
            // O^T: lane holds O[q][d = n*16 + 4g + r]
            *(u16x4*)(Oa + (q0w + c) * C_DIM + head * HD + n * 16 + 4 * g) = w0;
            *(u16x4*)(Oa + (q0w + 16 + c) * C_DIM + head * HD + n * 16 + 4 * g) = w1;
        }
        __syncthreads();  // all O writes issued; safe to reuse jw/sm for next job
    }
}

// ---------------- launch ----------------

extern "C" void kernel_launch(void* const* d_in, const int* in_sizes, int n_in,
                              void* d_out, int out_size, void* d_ws, size_t ws_size,
                              hipStream_t stream) {
    const float* x      = (const float*)d_in[0];
    const float* W_attn = (const float*)d_in[1];
    const float* b_attn = (const float*)d_in[2];
    const float* W_proj = (const float*)d_in[3];
    const float* b_proj = (const float*)d_in[4];
    float* out = (float*)d_out;

    char* ws = (char*)d_ws;
    u16* xb  = (u16*)(ws);                // 8 MB  x bf16 [4096][1024]
    u16* Wat = (u16*)(ws + (8u << 20));   // 6 MB  W_attn^T bf16 [3072][1024]
    u16* Wpt = (u16*)(ws + (14u << 20));  // 2 MB  W_proj^T bf16 [1024][1024]
    u16* Qb  = (u16*)(ws + (16u << 20));  // 8 MB  Q (pre-scaled) [16][4096][64]
    u16* Kb  = (u16*)(ws + (24u << 20));  // 8 MB  K [16][4096][64]
    u16* Vtb = (u16*)(ws + (32u << 20));  // 8 MB  V^T [16][64][4096]
    u16* Ab  = (u16*)(ws + (40u << 20));  // 8 MB  attn out bf16 [4096][1024]

    // job counter lives in d_out[0]: zeroed here, consumed by k_flash, then
    // overwritten by the proj GEMM epilogue (which writes every output element).
    unsigned* cnt = (unsigned*)d_out;
    hipMemsetAsync(cnt, 0, 4, stream);

    k_cvt_x<<<2048, 256, 0, stream>>>(x, xb);
    k_transpose_w<<<dim3(96, 32), dim3(32, 8), 0, stream>>>(W_attn, Wat, 1024, 3072);
    k_transpose_w<<<dim3(32, 32), dim3(32, 8), 0, stream>>>(W_proj, Wpt, 1024, 1024);
    k_gemm<0><<<768, 256, 0, stream>>>(xb, Wat, b_attn, Qb, Kb, Vtb, nullptr, 1024, 32);
    k_flash<<<1280, 128, 0, stream>>>(Qb, Kb, Vtb, Ab, cnt);
    k_gemm<1><<<256, 256, 0, stream>>>(Ab, Wpt, b_proj, nullptr, nullptr, nullptr, out, 1024, 32);
}